// Round 7
// baseline (78.108 us; speedup 1.0000x reference)
//
#include <hip/hip_runtime.h>
#include <math.h>

// Hash-grid (instant-NGP style) trilinear interpolation, layer 8.
// T = 2^19 entries x F=2 floats; N = 2^21 points x 3 dims.
// Hash: (ix ^ iy*2654435761 ^ iz*805459861) mod 2^19 -- uint32 math is
// bit-exact with the reference's int64 (power-of-two modulus).
//
// Evidence ledger:
//  r1/r3/r6 all ~62-65us across request counts 16.7M->12.6M, occupancy
//    69%->26%, batch depth 8->32: invariant = L1-missing gather granules.
//  r5: nt gathers broke L2 residency (FETCH 33->107MB, 2.2x slower) =>
//    table must stay L2-cached; FETCH ~30MB proves it normally is.
// This round: bypass L1 only. Agent-scope relaxed atomic loads compile to
// global_load_dwordx2 ... sc0 (no L1 allocate, L2 caching intact) --
// the supported-path version of round-4's crashed inline asm.

#define HT_MASK  524287u
#define PRIME_Y  2654435761u
#define PRIME_Z  805459861u
#define N_POINTS 2097152
#define PPT      4

typedef float vfloat4 __attribute__((ext_vector_type(4)));

union f2u64 {
    unsigned long long u;
    float2 f;
};

__global__ __launch_bounds__(256) void hashgrid_interp_kernel(
    const vfloat4* __restrict__ X4,              // N*3 floats viewed as float4
    const unsigned long long* __restrict__ tb,   // T x float2 as u64
    vfloat4* __restrict__ out4,                  // N x float2 viewed as float4
    float scale)
{
    int t = blockIdx.x * blockDim.x + threadIdx.x;   // 0 .. N/4-1

    // Points [4t, 4t+4): 12 floats = 3 aligned float4 loads (nontemporal:
    // X is streamed once; don't let it evict the table from L2).
    vfloat4 q0 = __builtin_nontemporal_load(&X4[3 * t + 0]);
    vfloat4 q1 = __builtin_nontemporal_load(&X4[3 * t + 1]);
    vfloat4 q2 = __builtin_nontemporal_load(&X4[3 * t + 2]);

    float px[PPT] = {q0.x, q0.w, q1.z, q2.y};
    float py[PPT] = {q0.y, q1.x, q1.w, q2.z};
    float pz[PPT] = {q0.z, q1.y, q2.x, q2.w};

    unsigned idx[PPT][8];
    float wx[PPT], wy[PPT], wz[PPT];

    #pragma unroll
    for (int p = 0; p < PPT; ++p) {
        float xs = px[p] * scale;
        float ys = py[p] * scale;
        float zs = pz[p] * scale;

        float fx = floorf(xs), fy = floorf(ys), fz = floorf(zs);
        wx[p] = xs - fx;  wy[p] = ys - fy;  wz[p] = zs - fz;

        unsigned hx0 = (unsigned)(int)fx;
        unsigned hy0 = (unsigned)(int)fy * PRIME_Y;
        unsigned hz0 = (unsigned)(int)fz * PRIME_Z;
        unsigned hx1 = (unsigned)(int)ceilf(xs);
        unsigned hy1 = (unsigned)(int)ceilf(ys) * PRIME_Y;
        unsigned hz1 = (unsigned)(int)ceilf(zs) * PRIME_Z;

        // corner c = (bx<<2)|(by<<1)|bz
        idx[p][0] = (hx0 ^ hy0 ^ hz0) & HT_MASK;
        idx[p][1] = (hx0 ^ hy0 ^ hz1) & HT_MASK;
        idx[p][2] = (hx0 ^ hy1 ^ hz0) & HT_MASK;
        idx[p][3] = (hx0 ^ hy1 ^ hz1) & HT_MASK;
        idx[p][4] = (hx1 ^ hy0 ^ hz0) & HT_MASK;
        idx[p][5] = (hx1 ^ hy0 ^ hz1) & HT_MASK;
        idx[p][6] = (hx1 ^ hy1 ^ hz0) & HT_MASK;
        idx[p][7] = (hx1 ^ hy1 ^ hz1) & HT_MASK;
    }

    // Issue all 32 gathers with agent scope (sc0: L1 bypass, L2 cached).
    f2u64 v[PPT][8];
    #pragma unroll
    for (int p = 0; p < PPT; ++p) {
        #pragma unroll
        for (int c = 0; c < 8; ++c) {
            v[p][c].u = __hip_atomic_load(
                (const unsigned long long*)&tb[idx[p][c]],
                __ATOMIC_RELAXED, __HIP_MEMORY_SCOPE_AGENT);
        }
    }

    float2 r[PPT];
    #pragma unroll
    for (int p = 0; p < PPT; ++p) {
        float omx = 1.0f - wx[p], omy = 1.0f - wy[p], omz = 1.0f - wz[p];

        float p00x = v[p][0].f.x * omx + v[p][4].f.x * wx[p];
        float p00y = v[p][0].f.y * omx + v[p][4].f.y * wx[p];
        float p01x = v[p][1].f.x * omx + v[p][5].f.x * wx[p];
        float p01y = v[p][1].f.y * omx + v[p][5].f.y * wx[p];
        float p10x = v[p][2].f.x * omx + v[p][6].f.x * wx[p];
        float p10y = v[p][2].f.y * omx + v[p][6].f.y * wx[p];
        float p11x = v[p][3].f.x * omx + v[p][7].f.x * wx[p];
        float p11y = v[p][3].f.y * omx + v[p][7].f.y * wx[p];

        float p0x = p00x * omy + p10x * wy[p];
        float p0y = p00y * omy + p10y * wy[p];
        float p1x = p01x * omy + p11x * wy[p];
        float p1y = p01y * omy + p11y * wy[p];

        r[p].x = p0x * omz + p1x * wz[p];
        r[p].y = p0y * omz + p1y * wz[p];
    }

    vfloat4 o0 = {r[0].x, r[0].y, r[1].x, r[1].y};
    vfloat4 o1 = {r[2].x, r[2].y, r[3].x, r[3].y};
    __builtin_nontemporal_store(o0, &out4[2 * t + 0]);
    __builtin_nontemporal_store(o1, &out4[2 * t + 1]);
}

extern "C" void kernel_launch(void* const* d_in, const int* in_sizes, int n_in,
                              void* d_out, int out_size, void* d_ws, size_t ws_size,
                              hipStream_t stream) {
    const vfloat4* X4 = (const vfloat4*)d_in[0];
    const unsigned long long* table = (const unsigned long long*)d_in[1];
    vfloat4* out4 = (vfloat4*)d_out;

    // RES computed exactly as the reference does (double precision on host).
    double growth = exp((log(512.0) - log(16.0)) / 15.0);
    double res = pow(growth, 8.0) * 16.0;
    float scale = (float)(res - 1.0);

    int block = 256;
    int grid = N_POINTS / (block * PPT);  // 2048 blocks
    hashgrid_interp_kernel<<<grid, block, 0, stream>>>(X4, table, out4, scale);
}